// Round 1
// baseline (455.087 us; speedup 1.0000x reference)
//
#include <hip/hip_runtime.h>
#include <math.h>

// Problem constants
#define NCOL 32768          // N = 32*32*32 columns
#define KAT  512            // dictionary atoms
#define DIM  64             // embedding dim

// Output flat offsets (fp32 elements)
#define O_LOSS  0
#define O_RECON 1
#define O_ZF    2097153     // 1 + 2097152
#define O_PERP  4194305
#define O_GAMMA 4194306

// Workspace layout (fp32 elements)
#define WS_DN   0           // Dn  [64][512]
#define WS_DNT  32768       // DnT [512][64]
#define WS_G    65536       // G   [512][512]
#define WS_ACC  327680      // acc[0]=sum((recon-zf)^2), acc[1]=sum_n S_n

// ---------------------------------------------------------------------------
// Kernel 1: normalize dictionary columns -> Dn, DnT; zero accumulators.
__global__ void prep_kernel(const float* __restrict__ dict, float* __restrict__ ws) {
    float* Dn  = ws + WS_DN;
    float* DnT = ws + WS_DNT;
    float* acc = ws + WS_ACC;
    int a = threadIdx.x;              // 512 threads, 1 block
    if (a < 2) acc[a] = 0.f;
    float s = 0.f;
    #pragma unroll
    for (int d = 0; d < DIM; ++d) { float v = dict[d*KAT + a]; s += v * v; }
    float nrm = sqrtf(s);
    #pragma unroll
    for (int d = 0; d < DIM; ++d) {
        float v = dict[d*KAT + a] / nrm;
        Dn[d*KAT + a]  = v;
        DnT[a*DIM + d] = v;
    }
}

// ---------------------------------------------------------------------------
// Kernel 2: G = Dn^T Dn.  block = row i (512 blocks), thread = col j (512).
__global__ void gram_kernel(const float* __restrict__ ws_in, float* __restrict__ ws) {
    const float* Dn = ws_in + WS_DN;
    float* G = ws + WS_G;
    int i = blockIdx.x, j = threadIdx.x;
    float s = 0.f;
    #pragma unroll
    for (int d = 0; d < DIM; ++d)
        s = fmaf(Dn[d*KAT + i], Dn[d*KAT + j], s);
    G[i*KAT + j] = s;
}

// ---------------------------------------------------------------------------
// Kernel 3: zf output = permutation gather of z_e, LDS-tiled for coalescing.
// out_zf[o] = z_e[b*65536 + c*1024 + h*32 + w], o = b<<16 | h<<11 | w<<6 | c
__global__ __launch_bounds__(256) void zf_kernel(const float* __restrict__ z_e,
                                                 float* __restrict__ out) {
    __shared__ float tile[64 * 33];   // [c][w], pad to 33 -> conflict-free
    int s = blockIdx.x;               // 1024 blocks: one (b,h) slab each
    int b = s >> 5, h = s & 31;
    int t = threadIdx.x;
    int srcbase = b * 65536 + h * 32;
    #pragma unroll
    for (int i = 0; i < 8; ++i) {
        int e = t + i * 256;          // e = c*32 + w
        int c = e >> 5, w = e & 31;
        tile[c * 33 + w] = z_e[srcbase + c * 1024 + w];
    }
    __syncthreads();
    int obase = O_ZF + s * 2048;
    #pragma unroll
    for (int i = 0; i < 8; ++i) {
        int e = t + i * 256;          // e = w*64 + c
        out[obase + e] = tile[(e & 63) * 33 + (e >> 6)];
    }
}

// ---------------------------------------------------------------------------
// Kernel 4: zero-fill gamma region (64 MiB). float2: region only 8B-aligned.
__global__ void gzero_kernel(float2* __restrict__ g2) {
    int id = blockIdx.x * 256 + threadIdx.x;   // 8192 blocks
    #pragma unroll
    for (int i = 0; i < 4; ++i)
        g2[id + i * 2097152] = make_float2(0.f, 0.f);
}

// ---------------------------------------------------------------------------
// Kernel 5: fused h_bar + Batch-OMP. 16 columns per 256-thread block.
// Phase 1: gather 16 data columns from z_e into LDS.
// Phase 2: h_bar[c][a] = sum_d Dn[d][a] * x[d][c] into LDS (Dn read once/block).
// Phase 3: each of 4 waves runs OMP for 4 columns (8 atoms/lane in registers,
//          Cholesky/solves replicated uniformly across lanes).
__global__ __launch_bounds__(256) void omp_kernel(const float* __restrict__ z_e,
                                                  const float* __restrict__ ws,
                                                  float* __restrict__ out,
                                                  float* __restrict__ wsw) {
    const float* Dn  = ws + WS_DN;
    const float* DnT = ws + WS_DNT;
    const float* G   = ws + WS_G;
    float* acc = wsw + WS_ACC;

    __shared__ float xcols[DIM * 16];     // [d][c]  4 KB
    __shared__ float hbar[16 * KAT];      // [c][a] 32 KB

    const int t = threadIdx.x;
    const int n_base = blockIdx.x * 16;

    // ---- Phase 1: gather data columns
    #pragma unroll
    for (int i = 0; i < 4; ++i) {
        int e = t + i * 256;              // 0..1023
        int d = e >> 4, c = e & 15;
        int L = d * NCOL + n_base + c;
        int src = (L >> 16) * 65536 + (L & 63) * 1024 + (((L >> 11) & 31) << 5) + ((L >> 6) & 31);
        xcols[e] = z_e[src];
    }
    __syncthreads();

    // ---- Phase 2: h_bar tile
    {
        float a0[16], a1[16];
        #pragma unroll
        for (int i = 0; i < 16; ++i) { a0[i] = 0.f; a1[i] = 0.f; }
        const float4* xc4 = (const float4*)xcols;
        for (int d = 0; d < DIM; ++d) {
            float v0 = Dn[d * KAT + t];
            float v1 = Dn[d * KAT + 256 + t];
            #pragma unroll
            for (int q = 0; q < 4; ++q) {
                float4 xv = xc4[d * 4 + q];
                a0[q*4+0] = fmaf(v0, xv.x, a0[q*4+0]);
                a0[q*4+1] = fmaf(v0, xv.y, a0[q*4+1]);
                a0[q*4+2] = fmaf(v0, xv.z, a0[q*4+2]);
                a0[q*4+3] = fmaf(v0, xv.w, a0[q*4+3]);
                a1[q*4+0] = fmaf(v1, xv.x, a1[q*4+0]);
                a1[q*4+1] = fmaf(v1, xv.y, a1[q*4+1]);
                a1[q*4+2] = fmaf(v1, xv.z, a1[q*4+2]);
                a1[q*4+3] = fmaf(v1, xv.w, a1[q*4+3]);
            }
        }
        #pragma unroll
        for (int c = 0; c < 16; ++c) {
            hbar[c * KAT + t]       = a0[c];
            hbar[c * KAT + 256 + t] = a1[c];
        }
    }
    __syncthreads();

    // ---- Phase 3: OMP, one wave per column, 4 columns sequentially
    const int wv = t >> 6, lane = t & 63;
    float wv_sq = 0.f, wv_S = 0.f;

    #pragma unroll 1
    for (int cc = 0; cc < 4; ++cc) {
        const int col = wv * 4 + cc;
        const int n = n_base + col;

        float hbv[8], hv[8];
        #pragma unroll
        for (int r = 0; r < 8; ++r) {
            hbv[r] = hbar[col * KAT + (r << 6) + lane];
            hv[r] = hbv[r];
        }
        unsigned msk = 0;
        float Lr[36];                 // lower-tri, row-major: L[i][j] @ i*(i+1)/2+j
        Lr[0] = 1.f;
        int Iv[8]; float hbs[8]; float xr[8];

        #pragma unroll
        for (int k = 0; k < 8; ++k) {
            // argmax |h| over unmasked, first-index tie-break (match jnp.argmax)
            float bv = -1.f; int bi = 0;
            #pragma unroll
            for (int r = 0; r < 8; ++r) {
                float av = ((msk >> r) & 1) ? -1.f : fabsf(hv[r]);
                if (av > bv) { bv = av; bi = (r << 6) | lane; }
            }
            #pragma unroll
            for (int off = 32; off; off >>= 1) {
                float ov = __shfl_xor(bv, off, 64);
                int   oi = __shfl_xor(bi, off, 64);
                if (ov > bv || (ov == bv && oi < bi)) { bv = ov; bi = oi; }
            }
            const int idx = bi;       // wave-uniform
            if ((idx & 63) == lane) msk |= 1u << (idx >> 6);

            // Cholesky rank-1 extension (replicated, uniform)
            if (k > 0) {
                float g[7], w[7];
                #pragma unroll
                for (int j = 0; j < 7; ++j) { if (j < k) g[j] = G[Iv[j] * KAT + idx]; }
                float s2 = 0.f;
                #pragma unroll
                for (int i = 0; i < 7; ++i) {
                    if (i < k) {
                        float a2 = g[i];
                        #pragma unroll
                        for (int j = 0; j < 7; ++j)
                            if (j < i) a2 -= Lr[i*(i+1)/2 + j] * w[j];
                        w[i] = a2 / Lr[i*(i+1)/2 + i];
                        s2 += w[i] * w[i];
                    }
                }
                #pragma unroll
                for (int j = 0; j < 7; ++j)
                    if (j < k) Lr[k*(k+1)/2 + j] = w[j];
                Lr[k*(k+1)/2 + k] = sqrtf(1.f - s2);
            }
            Iv[k] = idx;
            hbs[k] = hbar[col * KAT + idx];   // LDS broadcast

            // forward solve L y = hbs, back solve L^T x = y   (size k+1)
            float y[8];
            #pragma unroll
            for (int i = 0; i < 8; ++i) {
                if (i <= k) {
                    float a2 = hbs[i];
                    #pragma unroll
                    for (int j = 0; j < 8; ++j)
                        if (j < i) a2 -= Lr[i*(i+1)/2 + j] * y[j];
                    y[i] = a2 / Lr[i*(i+1)/2 + i];
                }
            }
            #pragma unroll
            for (int i = 7; i >= 0; --i) {
                if (i <= k) {
                    float a2 = y[i];
                    #pragma unroll
                    for (int j = 0; j < 8; ++j)
                        if (j > i && j <= k) a2 -= Lr[j*(j+1)/2 + i] * xr[j];
                    xr[i] = a2 / Lr[i*(i+1)/2 + i];
                }
            }

            // residual correlations: h = h_bar - G[:,I] @ xs   (skip after last)
            if (k < 7) {
                #pragma unroll
                for (int r = 0; r < 8; ++r) {
                    float a2 = hbv[r];
                    #pragma unroll
                    for (int j = 0; j < 8; ++j)
                        if (j <= k) a2 = fmaf(-xr[j], G[Iv[j] * KAT + (r << 6) + lane], a2);
                    hv[r] = a2;
                }
            }
        }

        // ---- outputs for this column ----
        // gamma scatter (zero-fill kernel already ran)
        #pragma unroll
        for (int j = 0; j < 8; ++j)
            if (lane == j) out[O_GAMMA + Iv[j] * NCOL + n] = xr[j];

        // recon (lane = d), write through the output permutation
        float rec = 0.f;
        #pragma unroll
        for (int j = 0; j < 8; ++j)
            rec = fmaf(xr[j], DnT[Iv[j] * DIM + lane], rec);
        int L = lane * NCOL + n;
        int perm = (L >> 16) * 65536 + (L & 63) * 1024 + (((L >> 11) & 31) << 5) + ((L >> 6) & 31);
        out[O_RECON + perm] = rec;

        // squared-error partial
        float xd = xcols[lane * 16 + col];
        float diff = rec - xd;
        float sq = diff * diff;
        #pragma unroll
        for (int off = 32; off; off >>= 1) sq += __shfl_xor(sq, off, 64);
        if (lane == 0) wv_sq += sq;

        // softmax-entropy term: 8 nnz + 504 zeros
        if (lane == 0) {
            float m = 0.f;
            #pragma unroll
            for (int j = 0; j < 8; ++j) m = fmaxf(m, xr[j]);
            float e0 = expf(-m);
            float Z = 504.f * e0;
            float es[8];
            #pragma unroll
            for (int j = 0; j < 8; ++j) { es[j] = expf(xr[j] - m); Z += es[j]; }
            float invZ = 1.f / Z;
            float p0 = e0 * invZ;
            float S = 504.f * p0 * logf(p0 + 1e-10f);
            #pragma unroll
            for (int j = 0; j < 8; ++j) { float p = es[j] * invZ; S += p * logf(p + 1e-10f); }
            wv_S += S;
        }
    }

    if (lane == 0) {
        atomicAdd(&acc[0], wv_sq);
        atomicAdd(&acc[1], wv_S);
    }
}

// ---------------------------------------------------------------------------
// Kernel 6: finalize scalars.
__global__ void fin_kernel(const float* __restrict__ ws, const float* __restrict__ beta,
                           float* __restrict__ out) {
    const float* acc = ws + WS_ACC;
    float mse = acc[0] / 2097152.f;                 // mean over 64*32768
    out[O_LOSS] = mse * 0.25f + beta[0] * mse;      // e_latent*cost + beta*q
    out[O_PERP] = expf(-acc[1] / 32768.f);
}

// ---------------------------------------------------------------------------
extern "C" void kernel_launch(void* const* d_in, const int* in_sizes, int n_in,
                              void* d_out, int out_size, void* d_ws, size_t ws_size,
                              hipStream_t stream) {
    const float* z_e  = (const float*)d_in[0];
    const float* dict = (const float*)d_in[1];
    const float* beta = (const float*)d_in[2];
    float* out = (float*)d_out;
    float* ws  = (float*)d_ws;

    prep_kernel<<<1, 512, 0, stream>>>(dict, ws);
    gram_kernel<<<512, 512, 0, stream>>>(ws, ws);
    zf_kernel<<<1024, 256, 0, stream>>>(z_e, out);
    gzero_kernel<<<8192, 256, 0, stream>>>((float2*)(out + O_GAMMA));
    omp_kernel<<<2048, 256, 0, stream>>>(z_e, ws, out, ws);
    fin_kernel<<<1, 1, 0, stream>>>(ws, beta, out);
}

// Round 2
// 381.028 us; speedup vs baseline: 1.1944x; 1.1944x over previous
//
#include <hip/hip_runtime.h>
#include <math.h>

// Problem constants
#define NCOL 32768          // N = 32*32*32 columns
#define KAT  512            // dictionary atoms
#define DIM  64             // embedding dim

// Output flat offsets (fp32 elements)
#define O_LOSS  0
#define O_RECON 1
#define O_ZF    2097153     // 1 + 2097152
#define O_PERP  4194305
#define O_GAMMA 4194306

// Workspace layout (fp32 elements)
#define WS_DN   0           // Dn  [64][512]
#define WS_DNT  32768       // DnT [512][64]
#define WS_G    65536       // G   [512][512]
#define WS_ACC  327680      // acc[0]=sum((recon-zf)^2), acc[1]=sum_n S_n

// ---------------------------------------------------------------------------
// Kernel 1: normalize dictionary columns -> Dn, DnT; zero accumulators.
__global__ void prep_kernel(const float* __restrict__ dict, float* __restrict__ ws) {
    float* Dn  = ws + WS_DN;
    float* DnT = ws + WS_DNT;
    float* acc = ws + WS_ACC;
    int a = threadIdx.x;              // 512 threads, 1 block
    if (a < 2) acc[a] = 0.f;
    float s = 0.f;
    #pragma unroll
    for (int d = 0; d < DIM; ++d) { float v = dict[d*KAT + a]; s += v * v; }
    float nrm = sqrtf(s);
    #pragma unroll
    for (int d = 0; d < DIM; ++d) {
        float v = dict[d*KAT + a] / nrm;
        Dn[d*KAT + a]  = v;
        DnT[a*DIM + d] = v;
    }
}

// ---------------------------------------------------------------------------
// Kernel 2: G = Dn^T Dn.  block = row i (512 blocks), thread = col j (512).
__global__ void gram_kernel(const float* __restrict__ ws_in, float* __restrict__ ws) {
    const float* Dn = ws_in + WS_DN;
    float* G = ws + WS_G;
    int i = blockIdx.x, j = threadIdx.x;
    float s = 0.f;
    #pragma unroll
    for (int d = 0; d < DIM; ++d)
        s = fmaf(Dn[d*KAT + i], Dn[d*KAT + j], s);
    G[i*KAT + j] = s;
}

// ---------------------------------------------------------------------------
// Kernel 3: zf output = permutation gather of z_e, LDS-tiled for coalescing.
__global__ __launch_bounds__(256) void zf_kernel(const float* __restrict__ z_e,
                                                 float* __restrict__ out) {
    __shared__ float tile[64 * 33];   // [c][w], pad to 33 -> conflict-free
    int s = blockIdx.x;               // 1024 blocks: one (b,h) slab each
    int b = s >> 5, h = s & 31;
    int t = threadIdx.x;
    int srcbase = b * 65536 + h * 32;
    #pragma unroll
    for (int i = 0; i < 8; ++i) {
        int e = t + i * 256;          // e = c*32 + w
        int c = e >> 5, w = e & 31;
        tile[c * 33 + w] = z_e[srcbase + c * 1024 + w];
    }
    __syncthreads();
    int obase = O_ZF + s * 2048;
    #pragma unroll
    for (int i = 0; i < 8; ++i) {
        int e = t + i * 256;          // e = w*64 + c
        out[obase + e] = tile[(e & 63) * 33 + (e >> 6)];
    }
}

// ---------------------------------------------------------------------------
// Kernel 4: zero-fill gamma region (64 MiB). float2: region only 8B-aligned.
__global__ void gzero_kernel(float2* __restrict__ g2) {
    int id = blockIdx.x * 256 + threadIdx.x;   // 8192 blocks
    #pragma unroll
    for (int i = 0; i < 4; ++i)
        g2[id + i * 2097152] = make_float2(0.f, 0.f);
}

// ---------------------------------------------------------------------------
// Kernel 5: fused h_bar + Batch-OMP with progressive orthogonalization.
// 16 columns per 256-thread block; one wave per column, 4 columns/wave.
// h is maintained incrementally: h -= y_k * u_k where
//   u_k = (G[idx,:] - sum_{j<k} L[k][j] u_j) / L[k][k]   (register-resident)
//   y_k = (h_bar[idx] - sum_{j<k} L[k][j] y_j) / L[k][k] (incremental fwd solve)
// Final xr from one back solve L^T xr = y. Divides replaced by invd[] mults.
__global__ __launch_bounds__(256) void omp_kernel(const float* __restrict__ z_e,
                                                  const float* __restrict__ ws,
                                                  float* __restrict__ out,
                                                  float* __restrict__ wsw) {
    const float* Dn  = ws + WS_DN;
    const float* DnT = ws + WS_DNT;
    const float* G   = ws + WS_G;
    float* acc = wsw + WS_ACC;

    __shared__ float xcols[DIM * 16];     // [d][c]  4 KB
    __shared__ float hbar[16 * KAT];      // [c][a] 32 KB

    const int t = threadIdx.x;
    const int n_base = blockIdx.x * 16;

    // ---- Phase 1: gather data columns
    #pragma unroll
    for (int i = 0; i < 4; ++i) {
        int e = t + i * 256;              // 0..1023
        int d = e >> 4, c = e & 15;
        int L = d * NCOL + n_base + c;
        int src = (L >> 16) * 65536 + (L & 63) * 1024 + (((L >> 11) & 31) << 5) + ((L >> 6) & 31);
        xcols[e] = z_e[src];
    }
    __syncthreads();

    // ---- Phase 2: h_bar tile (Dn read once per block)
    {
        float a0[16], a1[16];
        #pragma unroll
        for (int i = 0; i < 16; ++i) { a0[i] = 0.f; a1[i] = 0.f; }
        const float4* xc4 = (const float4*)xcols;
        for (int d = 0; d < DIM; ++d) {
            float v0 = Dn[d * KAT + t];
            float v1 = Dn[d * KAT + 256 + t];
            #pragma unroll
            for (int q = 0; q < 4; ++q) {
                float4 xv = xc4[d * 4 + q];
                a0[q*4+0] = fmaf(v0, xv.x, a0[q*4+0]);
                a0[q*4+1] = fmaf(v0, xv.y, a0[q*4+1]);
                a0[q*4+2] = fmaf(v0, xv.z, a0[q*4+2]);
                a0[q*4+3] = fmaf(v0, xv.w, a0[q*4+3]);
                a1[q*4+0] = fmaf(v1, xv.x, a1[q*4+0]);
                a1[q*4+1] = fmaf(v1, xv.y, a1[q*4+1]);
                a1[q*4+2] = fmaf(v1, xv.z, a1[q*4+2]);
                a1[q*4+3] = fmaf(v1, xv.w, a1[q*4+3]);
            }
        }
        #pragma unroll
        for (int c = 0; c < 16; ++c) {
            hbar[c * KAT + t]       = a0[c];
            hbar[c * KAT + 256 + t] = a1[c];
        }
    }
    __syncthreads();

    // ---- Phase 3: OMP
    const int wv = t >> 6, lane = t & 63;
    float wv_sq = 0.f, wv_S = 0.f;

    #pragma unroll 1
    for (int cc = 0; cc < 4; ++cc) {
        const int col = wv * 4 + cc;
        const int n = n_base + col;
        const float* hbcol = hbar + col * KAT;

        float h[8];
        #pragma unroll
        for (int r = 0; r < 8; ++r) h[r] = hbcol[(r << 6) + lane];

        unsigned msk = 0;
        float uv[56];                 // u_0..u_6, uv[k*8+r]
        float Lr[28];                 // off-diag rows 1..7: Lr[i*(i-1)/2+j], j<i
        float invd[8], yv[8], xr[8];
        int Iv[8];

        #pragma unroll
        for (int k = 0; k < 8; ++k) {
            // argmax |h| over unmasked; exact first-index tie-break via u64 key
            float bv = -1.f; int bi = 0;
            #pragma unroll
            for (int r = 0; r < 8; ++r) {
                float av = ((msk >> r) & 1) ? -1.f : fabsf(h[r]);
                if (av > bv) { bv = av; bi = (r << 6) | lane; }
            }
            unsigned long long key = (bv >= 0.f)
                ? ((((unsigned long long)__float_as_uint(bv)) << 32) | (unsigned)(511 - bi))
                : 0ull;
            #pragma unroll
            for (int off = 32; off; off >>= 1) {
                unsigned long long ok = __shfl_xor(key, off, 64);
                if (ok > key) key = ok;
            }
            const int idx = 511 - (int)(key & 511u);    // wave-uniform
            if ((idx & 63) == lane) msk |= 1u << (idx >> 6);

            const float* grow = G + idx * KAT;

            // prefetch the new G row (coalesced; also warms L1 for grow[Iv[j]])
            float gk[8];
            if (k < 7) {
                #pragma unroll
                for (int r = 0; r < 8; ++r) gk[r] = grow[(r << 6) + lane];
            }

            // Cholesky rank-1 extension (replicated, uniform)
            if (k == 0) {
                invd[0] = 1.f;
            } else {
                float w[7];
                #pragma unroll
                for (int i = 0; i < 7; ++i) if (i < k) {
                    float a = grow[Iv[i]];              // == G[Iv[i]][idx] (symmetric)
                    #pragma unroll
                    for (int j = 0; j < 7; ++j) if (j < i) a -= Lr[i*(i-1)/2 + j] * w[j];
                    w[i] = a * invd[i];
                }
                float s2 = 0.f;
                #pragma unroll
                for (int j = 0; j < 7; ++j) if (j < k) { Lr[k*(k-1)/2 + j] = w[j]; s2 += w[j]*w[j]; }
                invd[k] = 1.f / sqrtf(1.f - s2);
            }
            Iv[k] = idx;

            // incremental forward solve: y_k
            {
                float a = hbcol[idx];                   // LDS broadcast
                #pragma unroll
                for (int j = 0; j < 7; ++j) if (j < k) a -= Lr[k*(k-1)/2 + j] * yv[j];
                yv[k] = a * invd[k];
            }

            // u_k and incremental h update (not needed after last pick)
            if (k < 7) {
                #pragma unroll
                for (int r = 0; r < 8; ++r) {
                    float a = gk[r];
                    #pragma unroll
                    for (int j = 0; j < 7; ++j) if (j < k) a -= Lr[k*(k-1)/2 + j] * uv[j*8 + r];
                    a *= invd[k];
                    uv[k*8 + r] = a;
                    h[r] -= yv[k] * a;
                }
            }
        }

        // single back solve: L^T xr = yv
        #pragma unroll
        for (int i = 7; i >= 0; --i) {
            float a = yv[i];
            #pragma unroll
            for (int j = 0; j < 8; ++j) if (j > i) a -= Lr[j*(j-1)/2 + i] * xr[j];
            xr[i] = a * invd[i];
        }

        // ---- outputs for this column ----
        #pragma unroll
        for (int j = 0; j < 8; ++j)
            if (lane == j) out[O_GAMMA + Iv[j] * NCOL + n] = xr[j];

        // recon (lane = d), through the output permutation
        float rec = 0.f;
        #pragma unroll
        for (int j = 0; j < 8; ++j)
            rec = fmaf(xr[j], DnT[Iv[j] * DIM + lane], rec);
        int L = lane * NCOL + n;
        int perm = (L >> 16) * 65536 + (L & 63) * 1024 + (((L >> 11) & 31) << 5) + ((L >> 6) & 31);
        out[O_RECON + perm] = rec;

        // squared-error partial
        float xd = xcols[lane * 16 + col];
        float diff = rec - xd;
        float sq = diff * diff;
        #pragma unroll
        for (int off = 32; off; off >>= 1) sq += __shfl_xor(sq, off, 64);
        if (lane == 0) wv_sq += sq;

        // softmax-entropy term: 8 nnz + 504 zeros
        if (lane == 0) {
            float m = 0.f;
            #pragma unroll
            for (int j = 0; j < 8; ++j) m = fmaxf(m, xr[j]);
            float e0 = expf(-m);
            float Z = 504.f * e0;
            float es[8];
            #pragma unroll
            for (int j = 0; j < 8; ++j) { es[j] = expf(xr[j] - m); Z += es[j]; }
            float invZ = 1.f / Z;
            float p0 = e0 * invZ;
            float S = 504.f * p0 * logf(p0 + 1e-10f);
            #pragma unroll
            for (int j = 0; j < 8; ++j) { float p = es[j] * invZ; S += p * logf(p + 1e-10f); }
            wv_S += S;
        }
    }

    if (lane == 0) {
        atomicAdd(&acc[0], wv_sq);
        atomicAdd(&acc[1], wv_S);
    }
}

// ---------------------------------------------------------------------------
// Kernel 6: finalize scalars.
__global__ void fin_kernel(const float* __restrict__ ws, const float* __restrict__ beta,
                           float* __restrict__ out) {
    const float* acc = ws + WS_ACC;
    float mse = acc[0] / 2097152.f;                 // mean over 64*32768
    out[O_LOSS] = mse * 0.25f + beta[0] * mse;      // e_latent*cost + beta*q
    out[O_PERP] = expf(-acc[1] / 32768.f);
}

// ---------------------------------------------------------------------------
extern "C" void kernel_launch(void* const* d_in, const int* in_sizes, int n_in,
                              void* d_out, int out_size, void* d_ws, size_t ws_size,
                              hipStream_t stream) {
    const float* z_e  = (const float*)d_in[0];
    const float* dict = (const float*)d_in[1];
    const float* beta = (const float*)d_in[2];
    float* out = (float*)d_out;
    float* ws  = (float*)d_ws;

    prep_kernel<<<1, 512, 0, stream>>>(dict, ws);
    gram_kernel<<<512, 512, 0, stream>>>(ws, ws);
    zf_kernel<<<1024, 256, 0, stream>>>(z_e, out);
    gzero_kernel<<<8192, 256, 0, stream>>>((float2*)(out + O_GAMMA));
    omp_kernel<<<2048, 256, 0, stream>>>(z_e, ws, out, ws);
    fin_kernel<<<1, 1, 0, stream>>>(ws, beta, out);
}